// Round 1
// baseline (201.277 us; speedup 1.0000x reference)
//
#include <hip/hip_runtime.h>
#include <stdint.h>

// ---------------------------------------------------------------------------
// BinaryLinear: out[M,N] = x[M,K] @ sign(W[N,K])^T + bias[N]
// M=8192, K=2048, N=2048, fp32 in/out.
// Round 5: GEMM restructured to a deep-pipelined 256x256 tile:
//   - 512 threads (8 waves as 2x4), per-wave 128x64 output, 32x32x16 MFMA
//     (acc[4][2] f32x16), BK=32.
//   - 4-deep LDS ring (4 x 32KB = 128KB), prefetch distance 3 K-tiles via
//     global_load_lds; counted s_waitcnt vmcnt(12) in steady state (never 0
//     in the main loop) + raw s_barrier. Tail peels 3 tiles @ vmcnt(8/4/0).
//   - Swizzle for BK=32 (4 x 16B chunks/row): phys chunk = c ^ ((r>>1)&3),
//     applied on the *global* source address (LDS dest stays contiguous as
//     global_load_lds requires); ds_read_b128 frag reads are bank-optimal.
//   - setprio(1) around the MFMA cluster (T5; pays on phase-split schedules).
//   - Epilogue: direct scalar stores from the HW-verified 32x32 C/D mapping
//     (row=(reg&3)+8*(reg>>2)+4*(lane>>5), col=lane&31); 128B segments,
//     no LDS round-trip.
// Prep kernels (cvt_x, bin_w) unchanged from the verified Round-4 kernel.
// ---------------------------------------------------------------------------

typedef __bf16 bf16x8 __attribute__((ext_vector_type(8)));
typedef float f32x16 __attribute__((ext_vector_type(16)));

typedef const __attribute__((address_space(1))) void* gas_ptr;
typedef __attribute__((address_space(3))) void* lds_ptr;

__device__ __forceinline__ unsigned short f2bf_rne(float f) {
    unsigned int u = __builtin_bit_cast(unsigned int, f);
    u += 0x7fffu + ((u >> 16) & 1u);   // round-to-nearest-even
    return (unsigned short)(u >> 16);
}

// x fp32 -> bf16 bits, 8 elems/thread (two float4 loads, one uint4 store)
__global__ __launch_bounds__(256) void cvt_x_kernel(const float* __restrict__ in,
                                                    unsigned short* __restrict__ out,
                                                    int n8) {
    int i = blockIdx.x * 256 + threadIdx.x;
    if (i >= n8) return;
    const float4* p = reinterpret_cast<const float4*>(in + (size_t)i * 8);
    float4 f0 = p[0], f1 = p[1];
    union { unsigned short s[8]; uint4 v; } o;
    o.s[0] = f2bf_rne(f0.x); o.s[1] = f2bf_rne(f0.y);
    o.s[2] = f2bf_rne(f0.z); o.s[3] = f2bf_rne(f0.w);
    o.s[4] = f2bf_rne(f1.x); o.s[5] = f2bf_rne(f1.y);
    o.s[6] = f2bf_rne(f1.z); o.s[7] = f2bf_rne(f1.w);
    *reinterpret_cast<uint4*>(out + (size_t)i * 8) = o.v;
}

// W fp32 -> sign(W) as bf16 bits (+1.0/-1.0). w>=0 -> +1 per reference.
__global__ __launch_bounds__(256) void bin_w_kernel(const float* __restrict__ in,
                                                    unsigned short* __restrict__ out,
                                                    int n4) {
    int i = blockIdx.x * 256 + threadIdx.x;
    if (i >= n4) return;
    float4 f = reinterpret_cast<const float4*>(in)[i];
    union { unsigned short s[4]; uint2 v; } o;
    o.s[0] = (f.x >= 0.f) ? 0x3F80u : 0xBF80u;
    o.s[1] = (f.y >= 0.f) ? 0x3F80u : 0xBF80u;
    o.s[2] = (f.z >= 0.f) ? 0x3F80u : 0xBF80u;
    o.s[3] = (f.w >= 0.f) ? 0x3F80u : 0xBF80u;
    reinterpret_cast<uint2*>(out)[i] = o.v;
}

// ---------------------------------------------------------------------------
// GEMM: C[M,N] = A[M,K](bf16) * B[N,K]^T(bf16 +-1) + bias[N], fp32 out.
//
// Pipeline invariants (ring of 4 buffers, tile t lives in buf[t&3]):
//  - stage(t+3) targets buf[(t+3)&3] = buf[(t-1)&3]; tile t-1's ds_reads all
//    completed before its trailing barrier, which precedes this issue. Safe.
//  - vmcnt(12) after stage(t+3) leaves only stages t+1..t+3 (3 tiles x 4
//    loads) outstanding => stage(t) fully landed in THIS wave; the following
//    barrier makes that true for EVERY wave before any ds_read of tile t.
//  - Tail: t=KT-3/KT-2/KT-1 issue no stage; vmcnt(8)/(4)/(0).
// ---------------------------------------------------------------------------

#define WAITVM(N) asm volatile("s_waitcnt vmcnt(" #N ")" ::: "memory")

__device__ __forceinline__ void block_bar() {
    asm volatile("" ::: "memory");
    __builtin_amdgcn_s_barrier();
    asm volatile("" ::: "memory");
}

__global__ __launch_bounds__(512, 2) void gemm_bin_kernel(
    const unsigned short* __restrict__ A,   // bf16 bits [M][K]
    const unsigned short* __restrict__ B,   // bf16 bits [N][K]
    const float* __restrict__ bias,         // [N]
    float* __restrict__ C,                  // [M][N]
    int M, int N, int K)
{
    // 4 buffers x (A 16KB + B 16KB) = 128 KB
    __shared__ __align__(16) unsigned char smem_raw[131072];
    unsigned short* const sm = (unsigned short*)smem_raw;

    const int tid  = threadIdx.x;
    const int lane = tid & 63;
    const int wave = tid >> 6;    // 0..7
    const int wm   = wave >> 2;   // 0..1  (M half: 128 rows)
    const int wn   = wave & 3;    // 0..3  (N quarter: 64 cols)
    const int bm   = blockIdx.y;  // M/256 = 32
    const int bn   = blockIdx.x;  // N/256 = 8

    const unsigned short* __restrict__ Agb = A + (size_t)(bm * 256) * K;
    const unsigned short* __restrict__ Bgb = B + (size_t)(bn * 256) * K;

    const int lr = lane & 31;     // row within 32-tile (A) / col row (B)
    const int lk = lane >> 5;     // k-half: k = lk*8 + 0..7 within K=16 slice

    // Fragment LDS byte offsets (in ushort units), constant across K-tiles.
    // Row r has 4 chunks of 16B; logical chunk c stored at c ^ ((r>>1)&3).
    int offA[4][2], offB[2][2];
#pragma unroll
    for (int m = 0; m < 4; ++m) {
        const int r = wm * 128 + m * 32 + lr;
#pragma unroll
        for (int ks = 0; ks < 2; ++ks) {
            const int c = ks * 2 + lk;
            offA[m][ks] = (r * 4 + (c ^ ((r >> 1) & 3))) * 8;
        }
    }
#pragma unroll
    for (int n = 0; n < 2; ++n) {
        const int r = wn * 64 + n * 32 + lr;
#pragma unroll
        for (int ks = 0; ks < 2; ++ks) {
            const int c = ks * 2 + lk;
            offB[n][ks] = (r * 4 + (c ^ ((r >> 1) & 3))) * 8;
        }
    }

    // Staging geometry: thread stages physical 16B chunks g = j*512 + tid of
    // each operand tile (1024 chunks = 256 rows x 4). LDS dest is contiguous
    // (g*16B, wave-uniform base + lane*16 as the HW requires); the swizzle is
    // applied on the global source column.
    int goff[2], lso[2];
#pragma unroll
    for (int j = 0; j < 2; ++j) {
        const int g = j * 512 + tid;
        const int r = g >> 2;
        const int c = (g & 3) ^ ((r >> 1) & 3);
        goff[j] = r * K + c * 8;   // element offset within operand panel
        lso[j]  = g * 8;           // ushort offset within LDS tile
    }

    f32x16 acc[4][2];
#pragma unroll
    for (int m = 0; m < 4; ++m)
#pragma unroll
        for (int n = 0; n < 2; ++n)
#pragma unroll
            for (int r = 0; r < 16; ++r) acc[m][n][r] = 0.f;

    const int KT = K >> 5;   // 64 K-tiles of 32

    auto stage = [&](int ts) {
        unsigned short* lA = sm + (ts & 3) * 16384;
        unsigned short* lB = lA + 8192;
        const unsigned short* ga = Agb + (size_t)ts * 32;
        const unsigned short* gb = Bgb + (size_t)ts * 32;
        __builtin_amdgcn_global_load_lds((gas_ptr)(ga + goff[0]), (lds_ptr)(lA + lso[0]), 16, 0, 0);
        __builtin_amdgcn_global_load_lds((gas_ptr)(ga + goff[1]), (lds_ptr)(lA + lso[1]), 16, 0, 0);
        __builtin_amdgcn_global_load_lds((gas_ptr)(gb + goff[0]), (lds_ptr)(lB + lso[0]), 16, 0, 0);
        __builtin_amdgcn_global_load_lds((gas_ptr)(gb + goff[1]), (lds_ptr)(lB + lso[1]), 16, 0, 0);
    };

    auto compute = [&](int t) {
        const unsigned short* lA = sm + (t & 3) * 16384;
        const unsigned short* lB = lA + 8192;
        bf16x8 af[4][2], bf[2][2];
#pragma unroll
        for (int m = 0; m < 4; ++m)
#pragma unroll
            for (int ks = 0; ks < 2; ++ks)
                af[m][ks] = *reinterpret_cast<const bf16x8*>(lA + offA[m][ks]);
#pragma unroll
        for (int n = 0; n < 2; ++n)
#pragma unroll
            for (int ks = 0; ks < 2; ++ks)
                bf[n][ks] = *reinterpret_cast<const bf16x8*>(lB + offB[n][ks]);
        __builtin_amdgcn_s_setprio(1);
#pragma unroll
        for (int ks = 0; ks < 2; ++ks)
#pragma unroll
            for (int m = 0; m < 4; ++m)
#pragma unroll
                for (int n = 0; n < 2; ++n)
                    acc[m][n] = __builtin_amdgcn_mfma_f32_32x32x16_bf16(
                        af[m][ks], bf[n][ks], acc[m][n], 0, 0, 0);
        __builtin_amdgcn_s_setprio(0);
    };

    // Prologue: fill 3 tiles of the ring.
    stage(0); stage(1); stage(2);

    int t = 0;
    for (; t < KT - 3; ++t) {
        stage(t + 3);
        WAITVM(12);       // stages t+1..t+3 may remain in flight; tile t landed
        block_bar();
        compute(t);
        block_bar();      // all waves done reading buf[t&3] before it's restaged
    }
    // Tail: no more staging; ladder the vmcnt down.
    WAITVM(8);  block_bar(); compute(t); block_bar(); ++t;
    WAITVM(4);  block_bar(); compute(t); block_bar(); ++t;
    WAITVM(0);  block_bar(); compute(t);

    // Epilogue: direct stores. C/D layout (HW-verified, m74/m101):
    //   col = lane&31, row = (reg&3) + 8*(reg>>2) + 4*(lane>>5).
    // Each store instr covers 2 rows x 128B fully-written segments.
    const int colb = bn * 256 + wn * 64;
    const float bv0 = bias[colb + lr];
    const float bv1 = bias[colb + 32 + lr];
    const int r0 = bm * 256 + wm * 128 + 4 * lk;
#pragma unroll
    for (int m = 0; m < 4; ++m)
#pragma unroll
        for (int n = 0; n < 2; ++n) {
            const float bvn = n ? bv1 : bv0;
            float* cp = C + (size_t)(r0 + m * 32) * N + colb + n * 32 + lr;
#pragma unroll
            for (int r = 0; r < 16; ++r) {
                const int rr = (r & 3) + 8 * (r >> 2);
                cp[(size_t)rr * N] = acc[m][n][r] + bvn;
            }
        }
}

extern "C" void kernel_launch(void* const* d_in, const int* in_sizes, int n_in,
                              void* d_out, int out_size, void* d_ws, size_t ws_size,
                              hipStream_t stream) {
    const float* x    = (const float*)d_in[0];   // [M, K]
    const float* w    = (const float*)d_in[1];   // [N, K]
    const float* bias = (const float*)d_in[2];   // [N]
    float* out = (float*)d_out;

    const int K = 2048;                 // IN
    const int N = in_sizes[2];          // OUT = 2048
    const int M = in_sizes[0] / K;      // 8192

    unsigned short* xb = (unsigned short*)d_ws;   // [M,K] bf16: 32 MB
    unsigned short* wb = xb + (size_t)M * K;      // [N,K] bf16 +-1: 8 MB

    const int nx8 = (M * K) / 8;
    const int nw4 = (N * K) / 4;
    cvt_x_kernel<<<(nx8 + 255) / 256, 256, 0, stream>>>(x, xb, nx8);
    bin_w_kernel<<<(nw4 + 255) / 256, 256, 0, stream>>>(w, wb, nw4);

    dim3 grid(N / 256, M / 256);        // (8, 32) = 256 blocks = 1/CU
    gemm_bin_kernel<<<grid, 512, 0, stream>>>(xb, wb, bias, out, M, N, K);
}

// Round 2
// 193.426 us; speedup vs baseline: 1.0406x; 1.0406x over previous
//
#include <hip/hip_runtime.h>
#include <stdint.h>

// ---------------------------------------------------------------------------
// BinaryLinear: out[M,N] = x[M,K] @ sign(W[N,K])^T + bias[N]
// M=8192, K=2048, N=2048, fp32 in/out.
// Round 6: true 4-phase-per-K-tile interleaved schedule (T3+T4+T5 combo).
//   - 256x256 tile, 512 threads (8 waves 2x4), BK=64, 32x32x16 MFMA
//     (HW/harness-verified C/D + operand layouts carried from R4/R5).
//   - Phase = (M-half of wave output) x (K-half): {4-8 ds_read_b128 ||
//     stage 1 half-tile (2 gload_lds)} -> barrier -> lgkmcnt(0)+sched_barrier
//     -> setprio(1) -> 8 MFMA -> setprio(0) -> barrier.
//   - Half-tiles split along K (A-k0|A-k1|B-k0|B-k1, 16KB each): staging a
//     half-tile 5-6 phases before its first read makes vmcnt(8) provably
//     sufficient at every guard (odd-phase trailing barriers); vmcnt never
//     drains below 8 until the last two K-tiles (8 -> 4 -> 0 peel).
//   - 2-buffer LDS (128KB). Swizzle for 32-bf16 rows: phys chunk =
//     c ^ ((r>>1)&3), applied on the global source address (gload_lds dest
//     stays linear), giving 2-way (free) bank aliasing on frag reads.
//   - Epilogue: R5's direct scalar stores (no LDS round-trip).
// ---------------------------------------------------------------------------

typedef __bf16 bf16x8 __attribute__((ext_vector_type(8)));
typedef float f32x16 __attribute__((ext_vector_type(16)));

typedef const __attribute__((address_space(1))) void* gas_ptr;
typedef __attribute__((address_space(3))) void* lds_ptr;

__device__ __forceinline__ unsigned short f2bf_rne(float f) {
    unsigned int u = __builtin_bit_cast(unsigned int, f);
    u += 0x7fffu + ((u >> 16) & 1u);   // round-to-nearest-even
    return (unsigned short)(u >> 16);
}

// x fp32 -> bf16 bits, 8 elems/thread (two float4 loads, one uint4 store)
__global__ __launch_bounds__(256) void cvt_x_kernel(const float* __restrict__ in,
                                                    unsigned short* __restrict__ out,
                                                    int n8) {
    int i = blockIdx.x * 256 + threadIdx.x;
    if (i >= n8) return;
    const float4* p = reinterpret_cast<const float4*>(in + (size_t)i * 8);
    float4 f0 = p[0], f1 = p[1];
    union { unsigned short s[8]; uint4 v; } o;
    o.s[0] = f2bf_rne(f0.x); o.s[1] = f2bf_rne(f0.y);
    o.s[2] = f2bf_rne(f0.z); o.s[3] = f2bf_rne(f0.w);
    o.s[4] = f2bf_rne(f1.x); o.s[5] = f2bf_rne(f1.y);
    o.s[6] = f2bf_rne(f1.z); o.s[7] = f2bf_rne(f1.w);
    *reinterpret_cast<uint4*>(out + (size_t)i * 8) = o.v;
}

// W fp32 -> sign(W) as bf16 bits (+1.0/-1.0). w>=0 -> +1 per reference.
__global__ __launch_bounds__(256) void bin_w_kernel(const float* __restrict__ in,
                                                    unsigned short* __restrict__ out,
                                                    int n4) {
    int i = blockIdx.x * 256 + threadIdx.x;
    if (i >= n4) return;
    float4 f = reinterpret_cast<const float4*>(in)[i];
    union { unsigned short s[4]; uint2 v; } o;
    o.s[0] = (f.x >= 0.f) ? 0x3F80u : 0xBF80u;
    o.s[1] = (f.y >= 0.f) ? 0x3F80u : 0xBF80u;
    o.s[2] = (f.z >= 0.f) ? 0x3F80u : 0xBF80u;
    o.s[3] = (f.w >= 0.f) ? 0x3F80u : 0xBF80u;
    reinterpret_cast<uint2*>(out)[i] = o.v;
}

#define WAITVM(N) asm volatile("s_waitcnt vmcnt(" #N ")" ::: "memory")

__device__ __forceinline__ void block_bar() {
    asm volatile("" ::: "memory");
    __builtin_amdgcn_s_barrier();
    asm volatile("" ::: "memory");
}

// ---------------------------------------------------------------------------
// LDS map (ushort units), per buffer b (base = b*32768):
//   A-k0 @ +0      A-k1 @ +8192     B-k0 @ +16384    B-k1 @ +24576
// Each region: 256 rows x 32 bf16 (4 chunks of 16B/row), swizzled.
//
// Stage issue schedule (steady state, tile T being computed):
//   phase0: A-k1(T+1)   phase1: B-k1(T+1)   phase2: A-k0(T+2)   phase3: B-k0(T+2)
// Guards (before trailing barrier): phase1: vmcnt(8) [k1(T) landed],
//   phase3: vmcnt(8) [k0(T+1) landed]. Tail: vmcnt(8)/(4)/(0).
// ---------------------------------------------------------------------------
__global__ __launch_bounds__(512, 2) void gemm_bin_kernel(
    const unsigned short* __restrict__ A,   // bf16 bits [M][K]
    const unsigned short* __restrict__ B,   // bf16 bits [N][K]
    const float* __restrict__ bias,         // [N]
    float* __restrict__ C,                  // [M][N]
    int M, int N, int K)
{
    __shared__ __align__(16) unsigned char smem_raw[131072];
    unsigned short* const sm = (unsigned short*)smem_raw;

    const int tid  = threadIdx.x;
    const int lane = tid & 63;
    const int wave = tid >> 6;    // 0..7
    const int wm   = wave >> 2;   // 0..1  (M half: 128 rows)
    const int wn   = wave & 3;    // 0..3  (N quarter: 64 cols)
    const int bm   = blockIdx.y;  // 32
    const int bn   = blockIdx.x;  // 8

    const unsigned short* __restrict__ Agb = A + (size_t)(bm * 256) * K;
    const unsigned short* __restrict__ Bgb = B + (size_t)(bn * 256) * K;

    const int lr   = lane & 31;
    const int lkhi = lane >> 5;

    // Frag read offsets (ushort, relative to buffer base).
    int offA[2][2][2][2];   // [mh][mi][kh][kk]
    int offB[2][2][2];      // [ni][kh][kk]
#pragma unroll
    for (int mh = 0; mh < 2; ++mh)
#pragma unroll
        for (int mi = 0; mi < 2; ++mi) {
            const int r = wm * 128 + mh * 64 + mi * 32 + lr;
            const int s = (r >> 1) & 3;
#pragma unroll
            for (int kh = 0; kh < 2; ++kh)
#pragma unroll
                for (int kk = 0; kk < 2; ++kk)
                    offA[mh][mi][kh][kk] = kh * 8192 + (r * 4 + ((kk * 2 + lkhi) ^ s)) * 8;
        }
#pragma unroll
    for (int ni = 0; ni < 2; ++ni) {
        const int r = wn * 64 + ni * 32 + lr;
        const int s = (r >> 1) & 3;
#pragma unroll
        for (int kh = 0; kh < 2; ++kh)
#pragma unroll
            for (int kk = 0; kk < 2; ++kk)
                offB[ni][kh][kk] = 16384 + kh * 8192 + (r * 4 + ((kk * 2 + lkhi) ^ s)) * 8;
    }

    // Staging geometry: thread stages 2 chunks/half-tile (1024 chunks, 512 thr).
    int goff[2], lso[2];
#pragma unroll
    for (int j = 0; j < 2; ++j) {
        const int g = j * 512 + tid;
        const int r = g >> 2;
        const int c = (g & 3) ^ ((r >> 1) & 3);
        goff[j] = r * K + c * 8;    // element offset within (tile,khalf) panel
        lso[j]  = g * 8;            // ushort offset within LDS region
    }

    // Bias preload, pinned before the counted-vmcnt pipeline starts.
    const int colb = bn * 256 + wn * 64;
    float bv0 = bias[colb + lr];
    float bv1 = bias[colb + 32 + lr];
    asm volatile("" :: "v"(bv0), "v"(bv1));

    f32x16 acc[4][2];
#pragma unroll
    for (int m = 0; m < 4; ++m)
#pragma unroll
        for (int n = 0; n < 2; ++n)
#pragma unroll
            for (int r = 0; r < 16; ++r) acc[m][n][r] = 0.f;

    bf16x8 bfr[2][2];   // B frags for current k-half, persist across mh phases

    auto stage2 = [&](const unsigned short* gsrc, int ldsoff) {
#pragma unroll
        for (int j = 0; j < 2; ++j)
            __builtin_amdgcn_global_load_lds((gas_ptr)(gsrc + goff[j]),
                                             (lds_ptr)(sm + ldsoff + lso[j]), 16, 0, 0);
    };

    // One phase: ds-reads || stage -> bar -> lgkm0 -> prio1 -> 8 MFMA -> prio0.
    // Caller appends optional WAITVM + trailing block_bar().
    auto phase = [&](int bb, int mh, int kh, int readB,
                     const unsigned short* gsrc, int ldsoff, int dostage) {
        if (readB) {
#pragma unroll
            for (int ni = 0; ni < 2; ++ni)
#pragma unroll
                for (int kk = 0; kk < 2; ++kk)
                    bfr[ni][kk] = *reinterpret_cast<const bf16x8*>(
                        sm + bb + offB[ni][kh][kk]);
        }
        bf16x8 af[2][2];
#pragma unroll
        for (int mi = 0; mi < 2; ++mi)
#pragma unroll
            for (int kk = 0; kk < 2; ++kk)
                af[mi][kk] = *reinterpret_cast<const bf16x8*>(
                    sm + bb + offA[mh][mi][kh][kk]);
        if (dostage) stage2(gsrc, ldsoff);
        block_bar();
        asm volatile("s_waitcnt lgkmcnt(0)" ::: "memory");
        __builtin_amdgcn_sched_barrier(0);
        __builtin_amdgcn_s_setprio(1);
#pragma unroll
        for (int kk = 0; kk < 2; ++kk)
#pragma unroll
            for (int mi = 0; mi < 2; ++mi)
#pragma unroll
                for (int ni = 0; ni < 2; ++ni)
                    acc[mh * 2 + mi][ni] = __builtin_amdgcn_mfma_f32_32x32x16_bf16(
                        af[mi][kk], bfr[ni][kk], acc[mh * 2 + mi][ni], 0, 0, 0);
        __builtin_amdgcn_sched_barrier(0);
        __builtin_amdgcn_s_setprio(0);
    };

    const int KT = K >> 6;   // 32 K-tiles of 64

    // Prologue: k0(0), k1(0), k0(1) -- 12 loads; then ensure k0(0) landed.
    stage2(Agb,      0);
    stage2(Bgb,      16384);
    stage2(Agb + 32, 8192);
    stage2(Bgb + 32, 24576);
    stage2(Agb + 64, 32768);
    stage2(Bgb + 64, 32768 + 16384);
    WAITVM(8);
    block_bar();

    for (int T = 0; T < KT - 2; ++T) {
        const int bb = (T & 1) << 15;
        const int nb = bb ^ 32768;
        const unsigned short* gA1 = Agb + (size_t)(T + 1) * 64 + 32;  // A-k1(T+1)
        const unsigned short* gB1 = Bgb + (size_t)(T + 1) * 64 + 32;
        const unsigned short* gA0 = Agb + (size_t)(T + 2) * 64;       // A-k0(T+2)
        const unsigned short* gB0 = Bgb + (size_t)(T + 2) * 64;
        phase(bb, 0, 0, 1, gA1, nb + 8192,  1);            block_bar();
        phase(bb, 1, 0, 0, gB1, nb + 24576, 1); WAITVM(8); block_bar();
        phase(bb, 0, 1, 1, gA0, bb,         1);            block_bar();
        phase(bb, 1, 1, 0, gB0, bb + 16384, 1); WAITVM(8); block_bar();
    }
    {   // T = KT-2: stage only k1(KT-1); guards 8 then 4.
        const int bb = ((KT - 2) & 1) << 15;
        const int nb = bb ^ 32768;
        const unsigned short* gA1 = Agb + (size_t)(KT - 1) * 64 + 32;
        const unsigned short* gB1 = Bgb + (size_t)(KT - 1) * 64 + 32;
        phase(bb, 0, 0, 1, gA1, nb + 8192,  1);            block_bar();
        phase(bb, 1, 0, 0, gB1, nb + 24576, 1); WAITVM(8); block_bar();
        phase(bb, 0, 1, 1, Agb, 0,          0);            block_bar();
        phase(bb, 1, 1, 0, Agb, 0,          0); WAITVM(4); block_bar();
    }
    {   // T = KT-1: no staging; k1(KT-1) guard drains to 0.
        const int bb = ((KT - 1) & 1) << 15;
        phase(bb, 0, 0, 1, Agb, 0, 0);                     block_bar();
        phase(bb, 1, 0, 0, Agb, 0, 0);          WAITVM(0); block_bar();
        phase(bb, 0, 1, 1, Agb, 0, 0);                     block_bar();
        phase(bb, 1, 1, 0, Agb, 0, 0);
    }

    // Epilogue: direct stores. C/D layout (harness-verified R4/R5):
    //   col = lane&31, row = (reg&3) + 8*(reg>>2) + 4*(lane>>5).
    const float* bvp = bias;  (void)bvp;
    const int r0 = bm * 256 + wm * 128 + 4 * lkhi;
#pragma unroll
    for (int m = 0; m < 4; ++m)
#pragma unroll
        for (int n = 0; n < 2; ++n) {
            const float bvn = n ? bv1 : bv0;
            float* cp = C + (size_t)(r0 + m * 32) * N + colb + n * 32 + lr;
#pragma unroll
            for (int r = 0; r < 16; ++r) {
                const int rr = (r & 3) + 8 * (r >> 2);
                cp[(size_t)rr * N] = acc[m][n][r] + bvn;
            }
        }
}

extern "C" void kernel_launch(void* const* d_in, const int* in_sizes, int n_in,
                              void* d_out, int out_size, void* d_ws, size_t ws_size,
                              hipStream_t stream) {
    const float* x    = (const float*)d_in[0];   // [M, K]
    const float* w    = (const float*)d_in[1];   // [N, K]
    const float* bias = (const float*)d_in[2];   // [N]
    float* out = (float*)d_out;

    const int K = 2048;                 // IN
    const int N = in_sizes[2];          // OUT = 2048
    const int M = in_sizes[0] / K;      // 8192

    unsigned short* xb = (unsigned short*)d_ws;   // [M,K] bf16: 32 MB
    unsigned short* wb = xb + (size_t)M * K;      // [N,K] bf16 +-1: 8 MB

    const int nx8 = (M * K) / 8;
    const int nw4 = (N * K) / 4;
    cvt_x_kernel<<<(nx8 + 255) / 256, 256, 0, stream>>>(x, xb, nx8);
    bin_w_kernel<<<(nw4 + 255) / 256, 256, 0, stream>>>(w, wb, nw4);

    dim3 grid(N / 256, M / 256);        // (8, 32) = 256 blocks = 1/CU
    gemm_bin_kernel<<<grid, 512, 0, stream>>>(xb, wb, bias, out, M, N, K);
}